// Round 1
// baseline (1699.221 us; speedup 1.0000x reference)
//
#include <hip/hip_runtime.h>
#include <math.h>

#define VOCABC 256
static constexpr int Bn = 65536;
static constexpr int Sn = 128;
static constexpr int Pn = 512;
static constexpr int Dn = 1024;

// d_out layout (floats), in reference return order
static constexpr long long OFF_SIM = (long long)VOCABC * VOCABC;          // 65536
static constexpr long long OFF_TOP = OFF_SIM + (long long)Bn * Pn;        // 33619968
static constexpr long long OFF_USE = OFF_TOP + Bn;                        // 33685504
static constexpr long long OFF_CTX = OFF_USE + Pn;                        // 33686016

// ---------------- 1. co-occurrence histogram ----------------
__global__ void hist_kernel(const int* __restrict__ seq, float* __restrict__ cooc) {
    long long i4 = ((long long)blockIdx.x * 256 + threadIdx.x) * 4;
    const int4 v = *(const int4*)(seq + i4);
    int s = (int)(i4 & (Sn - 1));
    atomicAdd(cooc + v.x * VOCABC + v.y, 1.0f);
    atomicAdd(cooc + v.y * VOCABC + v.z, 1.0f);
    atomicAdd(cooc + v.z * VOCABC + v.w, 1.0f);
    if (s + 3 != Sn - 1) {
        int v4 = seq[i4 + 4];
        atomicAdd(cooc + v.w * VOCABC + v4, 1.0f);
    }
}

// ---------------- 2. row inverse norms ----------------
__global__ void rownorm_kernel(const float* __restrict__ x, float* __restrict__ inv, int rows) {
    int wave = threadIdx.x >> 6;
    int lane = threadIdx.x & 63;
    int row = blockIdx.x * 4 + wave;
    if (row >= rows) return;
    const float4* rp = (const float4*)(x + (long long)row * Dn);
    float ss = 0.f;
#pragma unroll
    for (int w = 0; w < Dn / 256; ++w) {
        float4 v = rp[w * 64 + lane];
        ss += v.x * v.x + v.y * v.y + v.z * v.z + v.w * v.w;
    }
#pragma unroll
    for (int off = 32; off; off >>= 1) ss += __shfl_xor(ss, off, 64);
    if (lane == 0) inv[row] = 1.0f / fmaxf(sqrtf(ss), 1e-8f);
}

// ---------------- 3. f32 GEMM: sim = (H . P^T) * invh * invp ----------------
#define BM 128
#define BN 128
#define BK 16
__global__ __launch_bounds__(256, 4) void gemm_kernel(
    const float* __restrict__ A,   // Bn x Dn
    const float* __restrict__ Bm,  // Pn x Dn
    const float* __restrict__ invh, const float* __restrict__ invp,
    float* __restrict__ sim) {
    __shared__ float As[BK][BM];
    __shared__ float Bs[BK][BN];
    int bx = blockIdx.x;
    int nb = bx & 3;     // Pn/BN = 4
    int mb = bx >> 2;
    int t = threadIdx.x;
    int lr = t >> 2;     // 0..63 (row within tile for staging)
    int lq = t & 3;      // k-quad within chunk
    const int m0 = mb * BM, n0 = nb * BN;
    int trow = (t >> 4) * 8;
    int tcol = (t & 15) * 8;

    float acc[8][8] = {};

    for (int kc = 0; kc < Dn; kc += BK) {
        float4 a0 = *(const float4*)(A + (long long)(m0 + lr) * Dn + kc + lq * 4);
        float4 a1 = *(const float4*)(A + (long long)(m0 + lr + 64) * Dn + kc + lq * 4);
        float4 b0 = *(const float4*)(Bm + (long long)(n0 + lr) * Dn + kc + lq * 4);
        float4 b1 = *(const float4*)(Bm + (long long)(n0 + lr + 64) * Dn + kc + lq * 4);
        __syncthreads();   // previous iteration's reads done before overwrite
        As[lq * 4 + 0][lr] = a0.x; As[lq * 4 + 1][lr] = a0.y;
        As[lq * 4 + 2][lr] = a0.z; As[lq * 4 + 3][lr] = a0.w;
        As[lq * 4 + 0][lr + 64] = a1.x; As[lq * 4 + 1][lr + 64] = a1.y;
        As[lq * 4 + 2][lr + 64] = a1.z; As[lq * 4 + 3][lr + 64] = a1.w;
        Bs[lq * 4 + 0][lr] = b0.x; Bs[lq * 4 + 1][lr] = b0.y;
        Bs[lq * 4 + 2][lr] = b0.z; Bs[lq * 4 + 3][lr] = b0.w;
        Bs[lq * 4 + 0][lr + 64] = b1.x; Bs[lq * 4 + 1][lr + 64] = b1.y;
        Bs[lq * 4 + 2][lr + 64] = b1.z; Bs[lq * 4 + 3][lr + 64] = b1.w;
        __syncthreads();
#pragma unroll
        for (int k = 0; k < BK; ++k) {
            float4 a01 = *(const float4*)&As[k][trow];
            float4 a23 = *(const float4*)&As[k][trow + 4];
            float4 b01 = *(const float4*)&Bs[k][tcol];
            float4 b23 = *(const float4*)&Bs[k][tcol + 4];
            float a[8] = {a01.x, a01.y, a01.z, a01.w, a23.x, a23.y, a23.z, a23.w};
            float b[8] = {b01.x, b01.y, b01.z, b01.w, b23.x, b23.y, b23.z, b23.w};
#pragma unroll
            for (int i = 0; i < 8; ++i)
#pragma unroll
                for (int j = 0; j < 8; ++j)
                    acc[i][j] = fmaf(a[i], b[j], acc[i][j]);
        }
    }

    float ih[8], ip[8];
#pragma unroll
    for (int i = 0; i < 8; ++i) ih[i] = invh[m0 + trow + i];
#pragma unroll
    for (int j = 0; j < 8; ++j) ip[j] = invp[n0 + tcol + j];
#pragma unroll
    for (int i = 0; i < 8; ++i) {
        float s0 = ih[i];
        float4 o0 = {acc[i][0] * s0 * ip[0], acc[i][1] * s0 * ip[1],
                     acc[i][2] * s0 * ip[2], acc[i][3] * s0 * ip[3]};
        float4 o1 = {acc[i][4] * s0 * ip[4], acc[i][5] * s0 * ip[5],
                     acc[i][6] * s0 * ip[6], acc[i][7] * s0 * ip[7]};
        long long base = (long long)(m0 + trow + i) * Pn + n0 + tcol;
        *(float4*)(sim + base) = o0;
        *(float4*)(sim + base + 4) = o1;
    }
}

// ---------------- 4. per-row argmax (first-index tie-break) ----------------
__global__ void argmax_kernel(const float* __restrict__ sim, float* __restrict__ topf,
                              int* __restrict__ topi, int* __restrict__ counts) {
    int wave = threadIdx.x >> 6, lane = threadIdx.x & 63;
    int row = blockIdx.x * 4 + wave;
    const float4* rp = (const float4*)(sim + (long long)row * Pn);
    float best = -INFINITY;
    int bi = 0;
#pragma unroll
    for (int w = 0; w < 2; ++w) {
        float4 v = rp[w * 64 + lane];
        int c0 = (w * 64 + lane) * 4;
        if (v.x > best) { best = v.x; bi = c0; }
        if (v.y > best) { best = v.y; bi = c0 + 1; }
        if (v.z > best) { best = v.z; bi = c0 + 2; }
        if (v.w > best) { best = v.w; bi = c0 + 3; }
    }
#pragma unroll
    for (int off = 32; off; off >>= 1) {
        float ov = __shfl_xor(best, off, 64);
        int oi = __shfl_xor(bi, off, 64);
        if (ov > best || (ov == best && oi < bi)) { best = ov; bi = oi; }
    }
    if (lane == 0) {
        topf[row] = (float)bi;
        topi[row] = bi;
        atomicAdd(counts + bi, 1);
    }
}

// ---------------- 5a. scan counts -> offsets, write usage ----------------
__global__ void scan_kernel(const int* __restrict__ counts, int* __restrict__ offsets,
                            float* __restrict__ usage) {
    __shared__ int sc[Pn];
    int t = threadIdx.x;
    int c = counts[t];
    usage[t] = (float)c;
    sc[t] = c;
    __syncthreads();
    for (int off = 1; off < Pn; off <<= 1) {
        int add = (t >= off) ? sc[t - off] : 0;
        __syncthreads();
        sc[t] += add;
        __syncthreads();
    }
    offsets[t] = sc[t] - c;   // exclusive
}

// ---------------- 5b. scatter row ids into buckets ----------------
__global__ void scatter_kernel(const int* __restrict__ topi, const int* __restrict__ offsets,
                               int* __restrict__ cursor, int* __restrict__ bucket) {
    int row = blockIdx.x * 256 + threadIdx.x;
    int p = topi[row];
    int pos = atomicAdd(cursor + p, 1);
    bucket[offsets[p] + pos] = row;
}

// ---------------- 5c. per-pattern accumulate context_sum ----------------
__global__ void accum_kernel(const float* __restrict__ hidden, const int* __restrict__ bucket,
                             const int* __restrict__ offsets, const int* __restrict__ counts,
                             float* __restrict__ ctx) {
    int p = blockIdx.x;
    int t = threadIdx.x;
    int off = offsets[p], cnt = counts[p];
    float4 acc = {0.f, 0.f, 0.f, 0.f};
    int r = 0;
    for (; r + 1 < cnt; r += 2) {
        int row0 = bucket[off + r];
        int row1 = bucket[off + r + 1];
        float4 v0 = *(const float4*)(hidden + (long long)row0 * Dn + t * 4);
        float4 v1 = *(const float4*)(hidden + (long long)row1 * Dn + t * 4);
        acc.x += v0.x + v1.x; acc.y += v0.y + v1.y;
        acc.z += v0.z + v1.z; acc.w += v0.w + v1.w;
    }
    if (r < cnt) {
        int row0 = bucket[off + r];
        float4 v0 = *(const float4*)(hidden + (long long)row0 * Dn + t * 4);
        acc.x += v0.x; acc.y += v0.y; acc.z += v0.z; acc.w += v0.w;
    }
    *(float4*)(ctx + (long long)p * Dn + t * 4) = acc;
}

extern "C" void kernel_launch(void* const* d_in, const int* in_sizes, int n_in,
                              void* d_out, int out_size, void* d_ws, size_t ws_size,
                              hipStream_t stream) {
    const int* seq = (const int*)d_in[0];
    const float* hidden = (const float*)d_in[1];
    const float* patterns = (const float*)d_in[2];

    float* out = (float*)d_out;
    float* cooc = out;
    float* sim = out + OFF_SIM;
    float* topf = out + OFF_TOP;
    float* usage = out + OFF_USE;
    float* ctx = out + OFF_CTX;

    float* invh = (float*)d_ws;            // Bn floats
    float* invp = invh + Bn;               // Pn floats
    int* topi = (int*)(invp + Pn);         // Bn ints
    int* counts = topi + Bn;               // Pn
    int* offsets = counts + Pn;            // Pn
    int* cursor = offsets + Pn;            // Pn
    int* bucket = cursor + Pn;             // Bn

    hipMemsetAsync(cooc, 0, (size_t)VOCABC * VOCABC * sizeof(float), stream);
    hipMemsetAsync(counts, 0, Pn * sizeof(int), stream);
    hipMemsetAsync(cursor, 0, Pn * sizeof(int), stream);

    hist_kernel<<<(Bn * Sn / 4) / 256, 256, 0, stream>>>(seq, cooc);
    rownorm_kernel<<<Bn / 4, 256, 0, stream>>>(hidden, invh, Bn);
    rownorm_kernel<<<Pn / 4, 256, 0, stream>>>(patterns, invp, Pn);
    gemm_kernel<<<(Bn / BM) * (Pn / BN), 256, 0, stream>>>(hidden, patterns, invh, invp, sim);
    argmax_kernel<<<Bn / 4, 256, 0, stream>>>(sim, topf, topi, counts);
    scan_kernel<<<1, Pn, 0, stream>>>(counts, offsets, usage);
    scatter_kernel<<<Bn / 256, 256, 0, stream>>>(topi, offsets, cursor, bucket);
    accum_kernel<<<Pn, 256, 0, stream>>>(hidden, bucket, offsets, counts, ctx);
}

// Round 3
// 1300.219 us; speedup vs baseline: 1.3069x; 1.3069x over previous
//
#include <hip/hip_runtime.h>
#include <math.h>

#define VOCABC 256
static constexpr int Bn = 65536;
static constexpr int Sn = 128;
static constexpr int Pn = 512;
static constexpr int Dn = 1024;

// d_out layout (floats), in reference return order
static constexpr long long OFF_SIM = (long long)VOCABC * VOCABC;          // 65536
static constexpr long long OFF_TOP = OFF_SIM + (long long)Bn * Pn;        // 33619968
static constexpr long long OFF_USE = OFF_TOP + Bn;                        // 33685504
static constexpr long long OFF_CTX = OFF_USE + Pn;                        // 33686016

// ---------------- 1a. co-occurrence: LDS-aggregated partial histograms ----------------
// 256 blocks: b = chunk*2 + half. Each block scans 512 rows, bins pairs whose
// first symbol is in its vocab half. LDS: 32768 u16 bins packed in 16384 u32
// (64 KB). Max per-bin count 512*127 = 65024 < 65535 -> no u16 overflow.
__global__ __launch_bounds__(256) void hist_part_kernel(const int* __restrict__ seq,
                                                        unsigned* __restrict__ partial) {
    __shared__ unsigned h[16384];
    int t = threadIdx.x, b = blockIdx.x;
    int half = b & 1;
    int chunk = b >> 1;
    for (int i = t; i < 16384; i += 256) h[i] = 0;
    __syncthreads();
#pragma unroll
    for (int rr = 0; rr < 2; ++rr) {
        int row = chunk * 512 + rr * 256 + t;
        const int4* rp = (const int4*)(seq + (long long)row * Sn);
        int prev = -1;
        for (int c = 0; c < Sn / 4; ++c) {
            int4 v = rp[c];
            int p0 = prev, p1 = v.x, p2 = v.y, p3 = v.z;
            int q0 = v.x, q1 = v.y, q2 = v.z, q3 = v.w;
            if (c && (p0 >> 7) == half) {
                int bin = (p0 & 127) * 256 + q0;
                atomicAdd(&h[bin >> 1], 1u << ((bin & 1) * 16));
            }
            if ((p1 >> 7) == half) {
                int bin = (p1 & 127) * 256 + q1;
                atomicAdd(&h[bin >> 1], 1u << ((bin & 1) * 16));
            }
            if ((p2 >> 7) == half) {
                int bin = (p2 & 127) * 256 + q2;
                atomicAdd(&h[bin >> 1], 1u << ((bin & 1) * 16));
            }
            if ((p3 >> 7) == half) {
                int bin = (p3 & 127) * 256 + q3;
                atomicAdd(&h[bin >> 1], 1u << ((bin & 1) * 16));
            }
            prev = v.w;
        }
    }
    __syncthreads();
    unsigned* outp = partial + (long long)b * 16384;
    for (int i = t; i < 16384; i += 256) outp[i] = h[i];
}

// ---------------- 1b. reduce partials -> cooc (writes every bin, no memset needed) --
__global__ void hist_reduce_kernel(const unsigned* __restrict__ partial,
                                   float* __restrict__ cooc) {
    int W = blockIdx.x * 128 + threadIdx.x;   // 0..32767 packed-word index
    int hf = W >> 14;                          // vocab half
    int wloc = W & 16383;
    unsigned lo = 0, hi = 0;
    for (int c = 0; c < 128; ++c) {
        unsigned v = partial[(long long)((c << 1) | hf) * 16384 + wloc];
        lo += v & 0xffffu;
        hi += v >> 16;
    }
    int v1 = (hf << 7) + (wloc >> 7);
    int v2 = (wloc & 127) * 2;
    cooc[v1 * VOCABC + v2] = (float)lo;
    cooc[v1 * VOCABC + v2 + 1] = (float)hi;
}

// ---------------- 2. row inverse norms ----------------
__global__ void rownorm_kernel(const float* __restrict__ x, float* __restrict__ inv, int rows) {
    int wave = threadIdx.x >> 6;
    int lane = threadIdx.x & 63;
    int row = blockIdx.x * 4 + wave;
    if (row >= rows) return;
    const float4* rp = (const float4*)(x + (long long)row * Dn);
    float ss = 0.f;
#pragma unroll
    for (int w = 0; w < Dn / 256; ++w) {
        float4 v = rp[w * 64 + lane];
        ss += v.x * v.x + v.y * v.y + v.z * v.z + v.w * v.w;
    }
#pragma unroll
    for (int off = 32; off; off >>= 1) ss += __shfl_xor(ss, off, 64);
    if (lane == 0) inv[row] = 1.0f / fmaxf(sqrtf(ss), 1e-8f);
}

// ---------------- 3. f32 GEMM: sim = (H . P^T) * invh * invp ----------------
// Conflict-free staging: thread t stages row (t>>1), k-half (t&1)*8 -> a wave's
// scalar LDS writes span 32 banks (2-way = free). Compute tile: 2x2 quadrants
// of 4x4 per thread -> every ds_read_b128 spreads over all 32 banks.
#define BM 128
#define BN 128
#define BK 16
__global__ __launch_bounds__(256, 4) void gemm_kernel(
    const float* __restrict__ A,   // Bn x Dn
    const float* __restrict__ Bm,  // Pn x Dn
    const float* __restrict__ invh, const float* __restrict__ invp,
    float* __restrict__ sim) {
    __shared__ float As[BK][BM];
    __shared__ float Bs[BK][BN];
    int bx = blockIdx.x;
    int nb = bx & 3;     // Pn/BN = 4
    int mb = bx >> 2;
    int t = threadIdx.x;
    int sr = t >> 1;         // staging row 0..127
    int sk = (t & 1) * 8;    // staging k offset 0 or 8
    const int m0 = mb * BM, n0 = nb * BN;
    int tp = t >> 4;         // 0..15
    int tq = t & 15;         // 0..15
    int trow = tp * 4;
    int tcol = tq * 4;

    const float* Ap = A + (long long)(m0 + sr) * Dn + sk;
    const float* Bp = Bm + (long long)(n0 + sr) * Dn + sk;

    float acc[2][2][4][4] = {};

    for (int kc = 0; kc < Dn; kc += BK) {
        float4 a0 = *(const float4*)(Ap + kc);
        float4 a1 = *(const float4*)(Ap + kc + 4);
        float4 b0 = *(const float4*)(Bp + kc);
        float4 b1 = *(const float4*)(Bp + kc + 4);
        __syncthreads();   // previous iteration's reads done before overwrite
        As[sk + 0][sr] = a0.x; As[sk + 1][sr] = a0.y;
        As[sk + 2][sr] = a0.z; As[sk + 3][sr] = a0.w;
        As[sk + 4][sr] = a1.x; As[sk + 5][sr] = a1.y;
        As[sk + 6][sr] = a1.z; As[sk + 7][sr] = a1.w;
        Bs[sk + 0][sr] = b0.x; Bs[sk + 1][sr] = b0.y;
        Bs[sk + 2][sr] = b0.z; Bs[sk + 3][sr] = b0.w;
        Bs[sk + 4][sr] = b1.x; Bs[sk + 5][sr] = b1.y;
        Bs[sk + 6][sr] = b1.z; Bs[sk + 7][sr] = b1.w;
        __syncthreads();
#pragma unroll
        for (int k = 0; k < BK; ++k) {
            float4 fa0 = *(const float4*)&As[k][trow];
            float4 fa1 = *(const float4*)&As[k][trow + 64];
            float4 fb0 = *(const float4*)&Bs[k][tcol];
            float4 fb1 = *(const float4*)&Bs[k][tcol + 64];
            float ar[2][4] = {{fa0.x, fa0.y, fa0.z, fa0.w}, {fa1.x, fa1.y, fa1.z, fa1.w}};
            float br[2][4] = {{fb0.x, fb0.y, fb0.z, fb0.w}, {fb1.x, fb1.y, fb1.z, fb1.w}};
#pragma unroll
            for (int ri = 0; ri < 2; ++ri)
#pragma unroll
                for (int i = 0; i < 4; ++i)
#pragma unroll
                    for (int ci = 0; ci < 2; ++ci)
#pragma unroll
                        for (int j = 0; j < 4; ++j)
                            acc[ri][ci][i][j] = fmaf(ar[ri][i], br[ci][j], acc[ri][ci][i][j]);
        }
    }

    float ih[2][4], ip[2][4];
#pragma unroll
    for (int ri = 0; ri < 2; ++ri)
#pragma unroll
        for (int i = 0; i < 4; ++i) ih[ri][i] = invh[m0 + trow + ri * 64 + i];
#pragma unroll
    for (int ci = 0; ci < 2; ++ci)
#pragma unroll
        for (int j = 0; j < 4; ++j) ip[ci][j] = invp[n0 + tcol + ci * 64 + j];
#pragma unroll
    for (int ri = 0; ri < 2; ++ri)
#pragma unroll
        for (int i = 0; i < 4; ++i) {
            long long row = m0 + trow + ri * 64 + i;
            float s0 = ih[ri][i];
#pragma unroll
            for (int ci = 0; ci < 2; ++ci) {
                float4 o = {acc[ri][ci][i][0] * s0 * ip[ci][0],
                            acc[ri][ci][i][1] * s0 * ip[ci][1],
                            acc[ri][ci][i][2] * s0 * ip[ci][2],
                            acc[ri][ci][i][3] * s0 * ip[ci][3]};
                *(float4*)(sim + row * Pn + n0 + tcol + ci * 64) = o;
            }
        }
}

// ---------------- 4. per-row argmax (first-index tie-break) ----------------
__global__ void argmax_kernel(const float* __restrict__ sim, float* __restrict__ topf,
                              int* __restrict__ topi, int* __restrict__ counts) {
    int wave = threadIdx.x >> 6, lane = threadIdx.x & 63;
    int row = blockIdx.x * 4 + wave;
    const float4* rp = (const float4*)(sim + (long long)row * Pn);
    float best = -INFINITY;
    int bi = 0;
#pragma unroll
    for (int w = 0; w < 2; ++w) {
        float4 v = rp[w * 64 + lane];
        int c0 = (w * 64 + lane) * 4;
        if (v.x > best) { best = v.x; bi = c0; }
        if (v.y > best) { best = v.y; bi = c0 + 1; }
        if (v.z > best) { best = v.z; bi = c0 + 2; }
        if (v.w > best) { best = v.w; bi = c0 + 3; }
    }
#pragma unroll
    for (int off = 32; off; off >>= 1) {
        float ov = __shfl_xor(best, off, 64);
        int oi = __shfl_xor(bi, off, 64);
        if (ov > best || (ov == best && oi < bi)) { best = ov; bi = oi; }
    }
    if (lane == 0) {
        topf[row] = (float)bi;
        topi[row] = bi;
        atomicAdd(counts + bi, 1);
    }
}

// ---------------- 5a. scan counts -> offsets, write usage ----------------
__global__ void scan_kernel(const int* __restrict__ counts, int* __restrict__ offsets,
                            float* __restrict__ usage) {
    __shared__ int sc[Pn];
    int t = threadIdx.x;
    int c = counts[t];
    usage[t] = (float)c;
    sc[t] = c;
    __syncthreads();
    for (int off = 1; off < Pn; off <<= 1) {
        int add = (t >= off) ? sc[t - off] : 0;
        __syncthreads();
        sc[t] += add;
        __syncthreads();
    }
    offsets[t] = sc[t] - c;   // exclusive
}

// ---------------- 5b. scatter row ids into buckets ----------------
__global__ void scatter_kernel(const int* __restrict__ topi, const int* __restrict__ offsets,
                               int* __restrict__ cursor, int* __restrict__ bucket) {
    int row = blockIdx.x * 256 + threadIdx.x;
    int p = topi[row];
    int pos = atomicAdd(cursor + p, 1);
    bucket[offsets[p] + pos] = row;
}

// ---------------- 5c. per-pattern accumulate context_sum ----------------
// grid = Pn*4 one-wave blocks: pattern p = bid>>2, D-chunk = bid&3.
// 4-row unroll keeps 4 independent loads in flight per thread.
__global__ void accum_kernel(const float* __restrict__ hidden, const int* __restrict__ bucket,
                             const int* __restrict__ offsets, const int* __restrict__ counts,
                             float* __restrict__ ctx) {
    int p = blockIdx.x >> 2;
    int cch = blockIdx.x & 3;
    int t = threadIdx.x;           // 0..63
    int off = offsets[p], cnt = counts[p];
    int col = cch * 256 + t * 4;
    float4 acc = {0.f, 0.f, 0.f, 0.f};
    int r = 0;
    for (; r + 4 <= cnt; r += 4) {
        int r0 = bucket[off + r + 0];
        int r1 = bucket[off + r + 1];
        int r2 = bucket[off + r + 2];
        int r3 = bucket[off + r + 3];
        float4 v0 = *(const float4*)(hidden + (long long)r0 * Dn + col);
        float4 v1 = *(const float4*)(hidden + (long long)r1 * Dn + col);
        float4 v2 = *(const float4*)(hidden + (long long)r2 * Dn + col);
        float4 v3 = *(const float4*)(hidden + (long long)r3 * Dn + col);
        acc.x += (v0.x + v1.x) + (v2.x + v3.x);
        acc.y += (v0.y + v1.y) + (v2.y + v3.y);
        acc.z += (v0.z + v1.z) + (v2.z + v3.z);
        acc.w += (v0.w + v1.w) + (v2.w + v3.w);
    }
    for (; r < cnt; ++r) {
        int r0 = bucket[off + r];
        float4 v0 = *(const float4*)(hidden + (long long)r0 * Dn + col);
        acc.x += v0.x; acc.y += v0.y; acc.z += v0.z; acc.w += v0.w;
    }
    *(float4*)(ctx + (long long)p * Dn + col) = acc;
}

extern "C" void kernel_launch(void* const* d_in, const int* in_sizes, int n_in,
                              void* d_out, int out_size, void* d_ws, size_t ws_size,
                              hipStream_t stream) {
    const int* seq = (const int*)d_in[0];
    const float* hidden = (const float*)d_in[1];
    const float* patterns = (const float*)d_in[2];

    float* out = (float*)d_out;
    float* cooc = out;
    float* sim = out + OFF_SIM;
    float* topf = out + OFF_TOP;
    float* usage = out + OFF_USE;
    float* ctx = out + OFF_CTX;

    float* invh = (float*)d_ws;            // Bn floats
    float* invp = invh + Bn;               // Pn floats
    int* topi = (int*)(invp + Pn);         // Bn ints
    int* counts = topi + Bn;               // Pn
    int* offsets = counts + Pn;            // Pn
    int* cursor = offsets + Pn;            // Pn
    int* bucket = cursor + Pn;             // Bn

    // hist partials live in the (not-yet-written) sim region of d_out:
    // 256 blocks * 16384 u32 = 16.7 MB << 128 MB sim region; gemm overwrites after.
    unsigned* partial = (unsigned*)sim;

    hipMemsetAsync(counts, 0, Pn * sizeof(int), stream);
    hipMemsetAsync(cursor, 0, Pn * sizeof(int), stream);

    hist_part_kernel<<<256, 256, 0, stream>>>(seq, partial);
    hist_reduce_kernel<<<256, 128, 0, stream>>>(partial, cooc);
    rownorm_kernel<<<Bn / 4, 256, 0, stream>>>(hidden, invh, Bn);
    rownorm_kernel<<<Pn / 4, 256, 0, stream>>>(patterns, invp, Pn);
    gemm_kernel<<<(Bn / BM) * (Pn / BN), 256, 0, stream>>>(hidden, patterns, invh, invp, sim);
    argmax_kernel<<<Bn / 4, 256, 0, stream>>>(sim, topf, topi, counts);
    scan_kernel<<<1, Pn, 0, stream>>>(counts, offsets, usage);
    scatter_kernel<<<Bn / 256, 256, 0, stream>>>(topi, offsets, cursor, bucket);
    accum_kernel<<<Pn * 4, 64, 0, stream>>>(hidden, bucket, offsets, counts, ctx);
}